// Round 4
// baseline (315.777 us; speedup 1.0000x reference)
//
#include <hip/hip_runtime.h>
#include <hip/hip_bf16.h>
#include <hip/hip_fp16.h>

#define N_NODES 50000
#define N_EDGES 800000
// IN_F = 64, D_ATT = 64, HEADS = 8, D_HEAD = 8
// outputs: attention [E,8] | v [N,64] | prods [E,8]  (all fp32)

typedef __attribute__((ext_vector_type(4))) unsigned int uint4v;
typedef __attribute__((ext_vector_type(2))) float f32x2;
typedef __attribute__((ext_vector_type(4))) float f32x4;
typedef __attribute__((ext_vector_type(2))) int   i32x2;

// dp-major table geometry (R10): Qb/Kb = [4][N_NODES][16] ushort, 1.6 MB per
// dp-slice; ssum = [4][N_NODES] half2; scratch = [4][N_EDGES] f32x2 (25.6 MB).
#define SLICE_U 800000            // 50000*16 ushorts per dp sub-table
#define SSUM_SLICE 50000
#define SCR_SLICE 1600000         // floats per dp scratch slice
#define WS_NEEDED 39200000u       // 6.4M*2 (Qb,Kb) + 0.8M (ssum) + 25.6M (scratch)

static __device__ __forceinline__ float bfu_lo(unsigned int u) {
    union { unsigned int u; float f; } v; v.u = u << 16; return v.f;
}
static __device__ __forceinline__ float bfu_hi(unsigned int u) {
    union { unsigned int u; float f; } v; v.u = u & 0xffff0000u; return v.f;
}
static __device__ __forceinline__ unsigned short f2bf(float f) {
    union { float f; unsigned int u; } v; v.f = f;
    v.u += 0x7fffu + ((v.u >> 16) & 1u);  // RNE
    return (unsigned short)(v.u >> 16);
}

// ---------------------------------------------------------------------------
// Kernel 1: fused Q/K/V projection + ssum zeroing. Compute unchanged; Q/K
// stores now go to dp-major sub-tables so each XCD's gather working set in
// edge_part is 3.2 MB (< 4 MB per-XCD L2). V fp32 NT.
// ---------------------------------------------------------------------------
__global__ __launch_bounds__(256, 2)
void proj_qkv(const float* __restrict__ x,
              const float* __restrict__ Wq, const float* __restrict__ bq,
              const float* __restrict__ Wk, const float* __restrict__ bk,
              const float* __restrict__ Wv, const float* __restrict__ bv,
              unsigned short* __restrict__ Qb, unsigned short* __restrict__ Kb,
              float* __restrict__ V, unsigned int* __restrict__ ssum_u)
{
    __shared__ float xs[32 * 64];  // 8 KB
    const int tid  = threadIdx.x;
    const int c    = tid & 63;      // output column 0..63  (h = c>>3, d = c&7)
    const int w    = tid >> 6;      // wave id 0..3
    const int row0 = blockIdx.x * 32;
    const int nrows = min(32, N_NODES - row0);

    // ssum zeroing: 200000 dwords (grid covers 1563*256 = 400128)
    {
        const int z = blockIdx.x * 256 + tid;
        if (z < N_NODES * 4) ssum_u[z] = 0u;
    }

    // stage x tile once (coalesced float4)
    {
        const float4* xg  = (const float4*)(x + (size_t)row0 * 64);
        float4*       xs4 = (float4*)xs;
        const int nf4 = nrows * 16;
        for (int i = tid; i < nf4; i += 256) xs4[i] = xg[i];
    }
    __syncthreads();

    const int r0 = w * 8;  // this wave's 8 rows

    float accq[8], acck[8], accv[8];
    {
        const float bqc = bq[c], bkc = bk[c], bvc = bv[c];
#pragma unroll
        for (int i = 0; i < 8; ++i) { accq[i] = bqc; acck[i] = bkc; accv[i] = bvc; }
    }

    for (int jc = 0; jc < 8; ++jc) {  // K-dim in chunks of 8
        float wq[8], wk[8], wv[8];
#pragma unroll
        for (int j = 0; j < 8; ++j) {
            const int row = (jc * 8 + j) * 64 + c;
            wq[j] = Wq[row]; wk[j] = Wk[row]; wv[j] = Wv[row];
        }
#pragma unroll
        for (int i = 0; i < 8; ++i) {
            const float4* xr = (const float4*)(xs + (r0 + i) * 64 + jc * 8);
            const float4 xv0 = xr[0], xv1 = xr[1];
            accq[i] += xv0.x * wq[0] + xv0.y * wq[1] + xv0.z * wq[2] + xv0.w * wq[3]
                     + xv1.x * wq[4] + xv1.y * wq[5] + xv1.z * wq[6] + xv1.w * wq[7];
            acck[i] += xv0.x * wk[0] + xv0.y * wk[1] + xv0.z * wk[2] + xv0.w * wk[3]
                     + xv1.x * wk[4] + xv1.y * wk[5] + xv1.z * wk[6] + xv1.w * wk[7];
            accv[i] += xv0.x * wv[0] + xv0.y * wv[1] + xv0.z * wv[2] + xv0.w * wv[3]
                     + xv1.x * wv[4] + xv1.y * wv[5] + xv1.z * wv[6] + xv1.w * wv[7];
        }
    }

    // dp-major store: sub-table dp = (d>>1) = (c&7)>>1, position within the
    // node's 32-B record: (d&1)*8 + h  (h-major within each d)
    const int dpc = (c & 7) >> 1;
    const int oc  = (c & 1) * 8 + (c >> 3);
    const size_t tb = (size_t)dpc * SLICE_U;
#pragma unroll
    for (int i = 0; i < 8; ++i) {
        const int r = r0 + i;
        if (r < nrows) {
            const size_t node = (size_t)(row0 + r);
            Qb[tb + node * 16 + oc] = f2bf(accq[i]);
            Kb[tb + node * 16 + oc] = f2bf(acck[i]);
            __builtin_nontemporal_store(accv[i], V + node * 64 + c);
        }
    }
}

// ---------------------------------------------------------------------------
// Kernel 2 (partitioned): one d-pair per block, dp bound to an XCD pair via
// dp = (blockIdx&7)>>1 (round-robin block->XCD). Per-XCD gather working set =
// Q-slice + K-slice = 3.2 MB < 4 MB L2 -> gathers become L2 hits instead of
// the ~57 MB of fabric re-fetch seen at R1-R9 (FETCH 76 MB vs 19 compulsory).
// Edge list NT (read-once stream, keep out of the 4 MB L2); p written to
// dp-major scratch with perfect 16-B coalescing (e-major prods write is
// impossible from a dp-partitioned block without 4x write inflation).
// Softmax max-shift skipped: |p| <= ~8, exp() safe in fp32; ratio identical.
// ---------------------------------------------------------------------------
__global__ __launch_bounds__(256)
void edge_part(const unsigned short* __restrict__ Qb,
               const unsigned short* __restrict__ Kb,
               const int* __restrict__ edge,
               float* __restrict__ scratch, __half2* __restrict__ ssum)
{
    const int b = blockIdx.x;
    const int dp = (b & 7) >> 1;              // XCD pair -> d-pair
    const int chunk = (b >> 3) * 2 + (b & 1); // [0, 1568)
    const int p = chunk * 256 + threadIdx.x;  // edge-pair index
    if (p >= N_EDGES / 2) return;
    const int eA = p * 2;

    const i32x2 esrc = __builtin_nontemporal_load((const i32x2*)(edge + eA));
    const i32x2 edst = __builtin_nontemporal_load((const i32x2*)(edge + N_EDGES + eA));

    const unsigned short* Qs = Qb + (size_t)dp * SLICE_U;
    const unsigned short* Ks = Kb + (size_t)dp * SLICE_U;
    const uint4v* qA = (const uint4v*)(Qs + (size_t)esrc.x * 16);
    const uint4v* kA = (const uint4v*)(Ks + (size_t)edst.x * 16);
    const uint4v* qB = (const uint4v*)(Qs + (size_t)esrc.y * 16);
    const uint4v* kB = (const uint4v*)(Ks + (size_t)edst.y * 16);
    const uint4v qA0 = qA[0], qA1 = qA[1];   // [d=2dp h0..7][d=2dp+1 h0..7]
    const uint4v kA0 = kA[0], kA1 = kA[1];
    const uint4v qB0 = qB[0], qB1 = qB[1];
    const uint4v kB0 = kB[0], kB1 = kB[1];

    float sA0 = 0.f, sA1 = 0.f, sB0 = 0.f, sB1 = 0.f;
#pragma unroll
    for (int i = 0; i < 4; ++i) {
        sA0 += bfu_lo(qA0[i]) * bfu_lo(kA0[i]) + bfu_hi(qA0[i]) * bfu_hi(kA0[i]);
        sA1 += bfu_lo(qA1[i]) * bfu_lo(kA1[i]) + bfu_hi(qA1[i]) * bfu_hi(kA1[i]);
        sB0 += bfu_lo(qB0[i]) * bfu_lo(kB0[i]) + bfu_hi(qB0[i]) * bfu_hi(kB0[i]);
        sB1 += bfu_lo(qB1[i]) * bfu_lo(kB1[i]) + bfu_hi(qB1[i]) * bfu_hi(kB1[i]);
    }

    const float cc = 0.35355339059327373f;  // 1/sqrt(8)
    const float pA0 = sA0 * cc, pA1 = sA1 * cc;
    const float pB0 = sB0 * cc, pB1 = sB1 * cc;
    // scratch[dp][eA..eA+1][2]: 16 contiguous bytes per thread, lane-consecutive
    __builtin_nontemporal_store((f32x4){pA0, pA1, pB0, pB1},
        (f32x4*)(scratch + (size_t)dp * SCR_SLICE + (size_t)p * 4));
    unsafeAtomicAdd(ssum + (size_t)dp * SSUM_SLICE + edst.x,
                    __floats2half2_rn(__expf(pA0), __expf(pA1)));
    unsafeAtomicAdd(ssum + (size_t)dp * SSUM_SLICE + edst.y,
                    __floats2half2_rn(__expf(pB0), __expf(pB1)));
}

// ---------------------------------------------------------------------------
// Kernel 3 (partitioned): 1 edge/thread transpose pass. Reads 4 coalesced
// dp-major scratch streams (NORMAL loads -- R9 lesson: NT loads on re-read
// paths cost ~7 us), ssum gather (800 KB, L2-resident per XCD), writes prods
// AND att e-major, NT (nothing re-reads outputs). Grid exact: 3125 blocks.
// ---------------------------------------------------------------------------
__global__ __launch_bounds__(256)
void norm_part(const int* __restrict__ edge, const float* __restrict__ scratch,
               const __half2* __restrict__ ssum,
               float* __restrict__ att, float* __restrict__ prods)
{
    const int e = blockIdx.x * 256 + threadIdx.x;  // [0, 800000) exact
    const int dst = edge[N_EDGES + e];

    const f32x2 p0 = *(const f32x2*)(scratch + 0 * SCR_SLICE + (size_t)e * 2);
    const f32x2 p1 = *(const f32x2*)(scratch + 1 * SCR_SLICE + (size_t)e * 2);
    const f32x2 p2 = *(const f32x2*)(scratch + 2 * SCR_SLICE + (size_t)e * 2);
    const f32x2 p3 = *(const f32x2*)(scratch + 3 * SCR_SLICE + (size_t)e * 2);
    const __half2 s0 = ssum[0 * SSUM_SLICE + dst];
    const __half2 s1 = ssum[1 * SSUM_SLICE + dst];
    const __half2 s2 = ssum[2 * SSUM_SLICE + dst];
    const __half2 s3 = ssum[3 * SSUM_SLICE + dst];

    __builtin_nontemporal_store((f32x4){p0.x, p0.y, p1.x, p1.y},
                                (f32x4*)(prods + (size_t)e * 8));
    __builtin_nontemporal_store((f32x4){p2.x, p2.y, p3.x, p3.y},
                                (f32x4*)(prods + (size_t)e * 8 + 4));

    f32x4 a0, a1;
    a0.x = __expf(p0.x) / (__low2float(s0)  + 1e-16f);
    a0.y = __expf(p0.y) / (__high2float(s0) + 1e-16f);
    a0.z = __expf(p1.x) / (__low2float(s1)  + 1e-16f);
    a0.w = __expf(p1.y) / (__high2float(s1) + 1e-16f);
    a1.x = __expf(p2.x) / (__low2float(s2)  + 1e-16f);
    a1.y = __expf(p2.y) / (__high2float(s2) + 1e-16f);
    a1.z = __expf(p3.x) / (__low2float(s3)  + 1e-16f);
    a1.w = __expf(p3.y) / (__high2float(s3) + 1e-16f);
    __builtin_nontemporal_store(a0, (f32x4*)(att + (size_t)e * 8));
    __builtin_nontemporal_store(a1, (f32x4*)(att + (size_t)e * 8 + 4));
}

// ---------------------------------------------------------------------------
// Fallback pair (used only if ws_size < 39.2 MB): R1 structure adapted to the
// dp-major table layout; no scratch needed. prods written/read with NORMAL
// ops (R9: the NT chain on prods/edge cost ~7 us in norm).
// ---------------------------------------------------------------------------
__global__ __launch_bounds__(256)
void edge_fb(const unsigned short* __restrict__ Qb,
             const unsigned short* __restrict__ Kb,
             const int* __restrict__ edge,
             float* __restrict__ prods, __half2* __restrict__ ssum)
{
    const int gid = blockIdx.x * 256 + threadIdx.x;  // [0, N_EDGES*2) exact
    const int e2 = gid >> 2;
    const int dp = gid & 3;
    const int eA = e2 * 2;

    const i32x2 esrc = *(const i32x2*)(edge + eA);
    const i32x2 edst = *(const i32x2*)(edge + N_EDGES + eA);

    const unsigned short* Qs = Qb + (size_t)dp * SLICE_U;
    const unsigned short* Ks = Kb + (size_t)dp * SLICE_U;
    const uint4v* qA = (const uint4v*)(Qs + (size_t)esrc.x * 16);
    const uint4v* kA = (const uint4v*)(Ks + (size_t)edst.x * 16);
    const uint4v* qB = (const uint4v*)(Qs + (size_t)esrc.y * 16);
    const uint4v* kB = (const uint4v*)(Ks + (size_t)edst.y * 16);
    const uint4v qA0 = qA[0], qA1 = qA[1];
    const uint4v kA0 = kA[0], kA1 = kA[1];
    const uint4v qB0 = qB[0], qB1 = qB[1];
    const uint4v kB0 = kB[0], kB1 = kB[1];

    float sA0 = 0.f, sA1 = 0.f, sB0 = 0.f, sB1 = 0.f;
#pragma unroll
    for (int i = 0; i < 4; ++i) {
        sA0 += bfu_lo(qA0[i]) * bfu_lo(kA0[i]) + bfu_hi(qA0[i]) * bfu_hi(kA0[i]);
        sA1 += bfu_lo(qA1[i]) * bfu_lo(kA1[i]) + bfu_hi(qA1[i]) * bfu_hi(kA1[i]);
        sB0 += bfu_lo(qB0[i]) * bfu_lo(kB0[i]) + bfu_hi(qB0[i]) * bfu_hi(kB0[i]);
        sB1 += bfu_lo(qB1[i]) * bfu_lo(kB1[i]) + bfu_hi(qB1[i]) * bfu_hi(kB1[i]);
    }

    const float cc = 0.35355339059327373f;
    const float pA0 = sA0 * cc, pA1 = sA1 * cc;
    const float pB0 = sB0 * cc, pB1 = sB1 * cc;
    *(f32x2*)(prods + (size_t)eA * 8 + dp * 2)       = (f32x2){pA0, pA1};
    *(f32x2*)(prods + (size_t)(eA + 1) * 8 + dp * 2) = (f32x2){pB0, pB1};
    unsafeAtomicAdd(ssum + (size_t)dp * SSUM_SLICE + edst.x,
                    __floats2half2_rn(__expf(pA0), __expf(pA1)));
    unsafeAtomicAdd(ssum + (size_t)dp * SSUM_SLICE + edst.y,
                    __floats2half2_rn(__expf(pB0), __expf(pB1)));
}

__global__ __launch_bounds__(256)
void norm_fb(const int* __restrict__ edge, const float* __restrict__ prods,
             const __half2* __restrict__ ssum, float* __restrict__ att)
{
    const int gid = blockIdx.x * 256 + threadIdx.x;
    const int e2 = gid >> 2;
    const int dp = gid & 3;
    const int eA = e2 * 2;

    const i32x2 edst = *(const i32x2*)(edge + N_EDGES + eA);
    const f32x2 pA = *(const f32x2*)(prods + (size_t)eA * 8 + dp * 2);
    const f32x2 pB = *(const f32x2*)(prods + (size_t)(eA + 1) * 8 + dp * 2);
    const __half2 sA = ssum[(size_t)dp * SSUM_SLICE + edst.x];
    const __half2 sB = ssum[(size_t)dp * SSUM_SLICE + edst.y];

    f32x2 rA, rB;
    rA.x = __expf(pA.x) / (__low2float(sA)  + 1e-16f);
    rA.y = __expf(pA.y) / (__high2float(sA) + 1e-16f);
    rB.x = __expf(pB.x) / (__low2float(sB)  + 1e-16f);
    rB.y = __expf(pB.y) / (__high2float(sB) + 1e-16f);
    __builtin_nontemporal_store(rA, (f32x2*)(att + (size_t)eA * 8 + dp * 2));
    __builtin_nontemporal_store(rB, (f32x2*)(att + (size_t)(eA + 1) * 8 + dp * 2));
}

extern "C" void kernel_launch(void* const* d_in, const int* in_sizes, int n_in,
                              void* d_out, int out_size, void* d_ws, size_t ws_size,
                              hipStream_t stream)
{
    const float* x    = (const float*)d_in[0];
    const float* Wq   = (const float*)d_in[1];
    const float* bq   = (const float*)d_in[2];
    const float* Wk   = (const float*)d_in[3];
    const float* bk   = (const float*)d_in[4];
    const float* Wv   = (const float*)d_in[5];
    const float* bv   = (const float*)d_in[6];
    const int*   edge = (const int*)d_in[7];

    float* out   = (float*)d_out;
    float* att   = out;                      // 6,400,000 floats
    float* V     = out + 6400000;            // 3,200,000 floats
    float* prods = out + 9600000;            // 6,400,000 floats

    unsigned short* Qb = (unsigned short*)d_ws;       // [4][50000][16] ushort
    unsigned short* Kb = Qb + 3200000;                // [4][50000][16] ushort
    __half2*        ssum = (__half2*)(Kb + 3200000);  // [4][50000] half2
    float*          scratch = (float*)(ssum + 200000);// [4][800000] f32x2 (25.6 MB)

    proj_qkv<<<(N_NODES + 31) / 32, 256, 0, stream>>>(
        x, Wq, bq, Wk, bk, Wv, bv, Qb, Kb, V, (unsigned int*)ssum);

    if (ws_size >= (size_t)WS_NEEDED) {
        // dp-partitioned path: 1568 chunks * 4 dp (as XCD pairs) = 6272 blocks
        edge_part<<<6272, 256, 0, stream>>>(Qb, Kb, edge, scratch, ssum);
        norm_part<<<N_EDGES / 256, 256, 0, stream>>>(edge, scratch, ssum, att,
                                                     prods);
    } else {
        const int nwork = N_EDGES * 2;
        edge_fb<<<nwork / 256, 256, 0, stream>>>(Qb, Kb, edge, prods, ssum);
        norm_fb<<<nwork / 256, 256, 0, stream>>>(edge, prods, ssum, att);
    }
}